// Round 1
// 259.040 us; speedup vs baseline: 1.0407x; 1.0407x over previous
//
#include <hip/hip_runtime.h>

#define CDIM 512
#define NH 8
#define HWDIM 4096
#define TILE 128   // spatial positions per block
#define NT 512     // threads per block = 8 waves

// Fold weights: wvT[c*8+n] = sum_j wqkv[(1024+64n+j)*512 + c]
//               wp [o*8+n] = sum_j wproj[o*512 + 64n + j]
__global__ __launch_bounds__(256) void prep_kernel(
    const float* __restrict__ wqkv, const float* __restrict__ wproj,
    float* __restrict__ wvT, float* __restrict__ wp) {
  int idx = blockIdx.x * 256 + threadIdx.x;
  if (idx < 4096) {
    int c = idx >> 3, n = idx & 7;
    const float* p = wqkv + (size_t)(1024 + n * 64) * CDIM + c;
    float s = 0.f;
#pragma unroll 8
    for (int j = 0; j < 64; ++j) s += p[(size_t)j * CDIM];
    wvT[idx] = s;
  } else if (idx < 8192) {
    int i2 = idx - 4096;
    int o = i2 >> 3, n = i2 & 7;
    const float* p = wproj + (size_t)o * CDIM + n * 64;
    float s = 0.f;
#pragma unroll 8
    for (int j = 0; j < 64; ++j) s += p[j];
    wp[i2] = s;
  }
}

// y[b,o,s] = bias[o] + sum_n wp[o,n] * (sum_c wvT[c,n] * x[b,c,s])
// 8 waves: phase 1 splits 512 channels 64/wave; phase 2 splits 512 outputs 64/wave.
// Lane owns 2 consecutive spatial positions (float2 loads/stores).
__global__ __launch_bounds__(NT, 4) void fused_kernel(
    const float* __restrict__ x, const float* __restrict__ bias,
    const float* __restrict__ wvT, const float* __restrict__ wp,
    float* __restrict__ y) {
  __shared__ __align__(16) float sWv[4096];            // [c][n]
  __shared__ __align__(16) float sWp[4096];            // [o][n]
  __shared__ __align__(16) float sB[512];
  __shared__ __align__(16) float sS[8][NH][TILE];      // per-wave partial S (32 KB)

  const int t = threadIdx.x;
  for (int i = t; i < 4096; i += NT) { sWv[i] = wvT[i]; sWp[i] = wp[i]; }
  if (t < 512) sB[t] = bias[t];
  __syncthreads();

  const int wave = t >> 6;
  const int lane = t & 63;
  const int pos0 = blockIdx.x * TILE;        // 128 | 4096 so blocks never straddle b
  const int b = pos0 >> 12;
  const int hw0 = pos0 & (HWDIM - 1);
  const float* xb = x + ((size_t)b * CDIM) * HWDIM + hw0 + lane * 2;

  // ---- phase 1: S[n, pos] partials; wave handles 64 channels ----
  float acc[NH][2];
#pragma unroll
  for (int n = 0; n < NH; ++n) { acc[n][0] = 0.f; acc[n][1] = 0.f; }

  const int c0 = wave * 64;
#pragma unroll 8
  for (int cc = 0; cc < 64; ++cc) {
    const int c = c0 + cc;
    const float2 xv = *(const float2*)(xb + (size_t)c * HWDIM);
    const float4 w0 = *(const float4*)&sWv[c * 8];
    const float4 w1 = *(const float4*)&sWv[c * 8 + 4];
    const float wn[8] = {w0.x, w0.y, w0.z, w0.w, w1.x, w1.y, w1.z, w1.w};
#pragma unroll
    for (int n = 0; n < NH; ++n) {
      acc[n][0] = fmaf(wn[n], xv.x, acc[n][0]);
      acc[n][1] = fmaf(wn[n], xv.y, acc[n][1]);
    }
  }

#pragma unroll
  for (int n = 0; n < NH; ++n) {
    *(float2*)&sS[wave][n][lane * 2] = make_float2(acc[n][0], acc[n][1]);
  }
  __syncthreads();

  // ---- phase 2: reduce S across 8 waves, expand to 512 outputs ----
  float S2[NH][2];
#pragma unroll
  for (int n = 0; n < NH; ++n) {
    float s0 = 0.f, s1 = 0.f;
#pragma unroll
    for (int w = 0; w < 8; ++w) {
      const float2 a = *(const float2*)&sS[w][n][lane * 2];
      s0 += a.x; s1 += a.y;
    }
    S2[n][0] = s0; S2[n][1] = s1;
  }

  float* yb = y + ((size_t)b * CDIM) * HWDIM + hw0 + lane * 2;
  const int o0 = wave * 64;
#pragma unroll 4
  for (int oo = 0; oo < 64; ++oo) {
    const int o = o0 + oo;
    const float4 w0 = *(const float4*)&sWp[o * 8];
    const float4 w1 = *(const float4*)&sWp[o * 8 + 4];
    const float wn[8] = {w0.x, w0.y, w0.z, w0.w, w1.x, w1.y, w1.z, w1.w};
    const float bb = sB[o];
    float r0 = bb, r1 = bb;
#pragma unroll
    for (int n = 0; n < NH; ++n) {
      r0 = fmaf(wn[n], S2[n][0], r0);
      r1 = fmaf(wn[n], S2[n][1], r1);
    }
    *(float2*)(yb + (size_t)o * HWDIM) = make_float2(r0, r1);
  }
}

extern "C" void kernel_launch(void* const* d_in, const int* in_sizes, int n_in,
                              void* d_out, int out_size, void* d_ws, size_t ws_size,
                              hipStream_t stream) {
  const float* x     = (const float*)d_in[0];
  const float* wqkv  = (const float*)d_in[1];
  const float* wproj = (const float*)d_in[2];
  const float* bproj = (const float*)d_in[3];
  float* y = (float*)d_out;

  float* wvT = (float*)d_ws;        // 4096 floats
  float* wp  = wvT + 4096;          // 4096 floats (32 KB total scratch)

  prep_kernel<<<32, 256, 0, stream>>>(wqkv, wproj, wvT, wp);
  fused_kernel<<<HWDIM * 16 / TILE, NT, 0, stream>>>(x, bproj, wvT, wp, y);
}